// Round 4
// baseline (137.273 us; speedup 1.0000x reference)
//
#include <hip/hip_runtime.h>
#include <math.h>

// SO3 convolution lmax=2 — 2-dispatch pipeline, block-per-atom.
//   K1) csr_kernel: ONE block (1024 thr). LDS histogram of idx_i; one 32-bit
//       shfl wave-scan (2 barriers) -> offsets[A+1]; scatter into a 48 KB LDS
//       staging buffer; coalesced dump -> esorted. No chunk machinery.
//   K2) so3_atom_kernel: grid = A, one 64-thread wave per atom. Loops over
//       tiles of TEDGE=8 edges, register accumulator persists across tiles:
//         stage (Ysh, radial, cutoff, j) -> B1 radial filters for 8 slots in
//         one Wf pass (registers) -> B2 sparse-CG M[9][12] per edge in LDS
//         -> C branch-free unrolled 8-edge contraction.
//       Tail slots are exact zeros (cut=0, rad=0, M=0, j=self). Every atom
//       stores its full out row once (deg-0 atoms store zeros). No slots,
//       no reduce kernel, no atomics on global, no memsets.

#define S9     9
#define MROW   12          // padded M row stride (floats)
#define NF     128
#define NRAD   20
#define TEDGE  8           // edges per tile
#define MAXA   2048
#define EMAX   12288       // LDS staging capacity for esorted

__device__ inline float2 f2fma(float a, float2 b, float2 c) {
    return make_float2(fmaf(a, b.x, c.x), fmaf(a, b.y, c.y));
}

// ---------- K1: CSR build (single block, 1024 threads, A <= 2048) ----------
__global__ __launch_bounds__(1024) void csr_kernel(
    const int* __restrict__ idx_i, int E, int A,
    int* __restrict__ offsets,      // [A+1]
    int* __restrict__ esorted)      // [E]
{
    __shared__ int lcnt[MAXA];      // counts, then reused as scatter cursors
    __shared__ int wtot[16];
    __shared__ int esh[EMAX];       // LDS-staged esorted (coalesced dump)
    const int t = threadIdx.x;
    const int lane = t & 63;
    const int wid  = t >> 6;

    for (int i = t; i < A; i += 1024) lcnt[i] = 0;
    __syncthreads();
    for (int e = t; e < E; e += 1024) atomicAdd(&lcnt[idx_i[e]], 1);
    __syncthreads();

    const int i0 = 2 * t, i1 = 2 * t + 1;
    const int ca = (i0 < A) ? lcnt[i0] : 0;
    const int cb = (i1 < A) ? lcnt[i1] : 0;
    __syncthreads();                 // all reads done before cursor overwrite

    // wave-level inclusive scan of (ca+cb), then 16-wave combine
    int inc = ca + cb;
    #pragma unroll
    for (int d = 1; d < 64; d <<= 1) {
        int u = __shfl_up(inc, d);
        if (lane >= d) inc += u;
    }
    if (lane == 63) wtot[wid] = inc;
    __syncthreads();
    if (wid == 0) {
        int w = (lane < 16) ? wtot[lane] : 0;
        #pragma unroll
        for (int d = 1; d < 16; d <<= 1) {
            int u = __shfl_up(w, d);
            if (lane >= d) w += u;
        }
        if (lane < 16) wtot[lane] = w;   // inclusive over wave totals
    }
    __syncthreads();
    int run = ((wid > 0) ? wtot[wid - 1] : 0) + (inc - (ca + cb));
    if (i0 < A) { offsets[i0] = run; lcnt[i0] = run; run += ca; }
    if (i1 < A) { offsets[i1] = run; lcnt[i1] = run; run += cb; }
    if (t == 1023) offsets[A] = wtot[15];
    __syncthreads();

    if (E <= EMAX) {
        for (int e = t; e < E; e += 1024) {
            int p = atomicAdd(&lcnt[idx_i[e]], 1);
            esh[p] = e;
        }
        __syncthreads();
        for (int i = t; i < E; i += 1024) esorted[i] = esh[i];   // coalesced
    } else {
        for (int e = t; e < E; e += 1024) {
            int p = atomicAdd(&lcnt[idx_i[e]], 1);
            esorted[p] = e;
        }
    }
}

// ---------- K2: one wave per atom, tiled over TEDGE-edge groups ----------
__global__ __launch_bounds__(64) void so3_atom_kernel(
    const float* __restrict__ x,        // [A, 9, 128]
    const float* __restrict__ radial,   // [E, 20]
    const float* __restrict__ dir,      // [E, 3]
    const float* __restrict__ cutoff,   // [E]
    const float* __restrict__ Wf,       // [20, 384]
    const float* __restrict__ bf,       // [384]
    const float* __restrict__ cg_vals,
    const int* __restrict__ idx_j,
    const int* __restrict__ cg_i1,
    const int* __restrict__ cg_i2,
    const int* __restrict__ cg_i3,
    int ncg,
    const int* __restrict__ offsets,    // [A+1]
    const int* __restrict__ esorted,    // [E]
    float* __restrict__ out)            // [A, 9, 128]
{
    const int a = blockIdx.x;
    const int t = threadIdx.x;           // f-pair index: f = 2t, 2t+1
    const int e0 = offsets[a];
    const int e1 = offsets[a + 1];

    __shared__ __align__(16) float M[TEDGE][MROW * S9];
    __shared__ float Ysh[TEDGE][S9];
    __shared__ float radsh[TEDGE][NRAD];
    __shared__ float cutsh[TEDGE];
    __shared__ int   jsh[TEDGE];

    float2 acc[S9];
    #pragma unroll
    for (int s = 0; s < S9; ++s) acc[s] = make_float2(0.f, 0.f);

    // bias rows are tile-invariant
    const float2 b0 = ((const float2*)(bf + 0 * NF))[t];
    const float2 b1 = ((const float2*)(bf + 1 * NF))[t];
    const float2 b2 = ((const float2*)(bf + 2 * NF))[t];

    for (int base = e0; base < e1; base += TEDGE) {
        const int n = min(TEDGE, e1 - base);

        // ---- stage: zero M, per-slot metadata, SH, radial ----
        {
            float4* Mz = (float4*)&M[0][0];
            const int tot4 = TEDGE * MROW * S9 / 4;   // 216
            for (int qq = t; qq < tot4; qq += 64) Mz[qq] = make_float4(0.f, 0.f, 0.f, 0.f);
        }
        if (t < TEDGE) {
            int jj = a;              // tail slots: any valid row (contribution is 0)
            float cut = 0.f;
            if (t < n) {
                const int e = esorted[base + t];
                jj = idx_j[e];
                cut = cutoff[e];
                float dx = dir[3 * e], dy = dir[3 * e + 1], dz = dir[3 * e + 2];
                const float inv = rsqrtf(dx * dx + dy * dy + dz * dz);
                dx *= inv; dy *= inv; dz *= inv;
                const float s3c  = 1.7320508075688772f;
                const float s5c  = 2.2360679774997896f;
                const float s15c = 3.8729833462074170f;
                Ysh[t][0] = 1.0f;
                Ysh[t][1] = s3c * dy;
                Ysh[t][2] = s3c * dz;
                Ysh[t][3] = s3c * dx;
                Ysh[t][4] = s15c * dx * dy;
                Ysh[t][5] = s15c * dy * dz;
                Ysh[t][6] = 0.5f * s5c * (3.0f * dz * dz - 1.0f);
                Ysh[t][7] = s15c * dx * dz;
                Ysh[t][8] = 0.5f * s15c * (dx * dx - dy * dy);
            }
            jsh[t] = jj;
            cutsh[t] = cut;
        }
        for (int qq = t; qq < TEDGE * NRAD; qq += 64) {
            const int c = qq / NRAD;
            const int r = qq - c * NRAD;
            radsh[c][r] = (c < n) ? radial[(size_t)esorted[base + c] * NRAD + r] : 0.f;
        }
        __syncthreads();

        // ---- B1: radial filters for 8 slots in one Wf pass (registers) ----
        float2 w[TEDGE][3];
        #pragma unroll
        for (int c = 0; c < TEDGE; ++c) { w[c][0] = b0; w[c][1] = b1; w[c][2] = b2; }
        #pragma unroll 4
        for (int r = 0; r < NRAD; ++r) {
            const float2* wrow = (const float2*)(Wf + r * (3 * NF));
            const float2 w0 = wrow[t];
            const float2 w1 = wrow[t + 64];
            const float2 w2 = wrow[t + 128];
            #pragma unroll
            for (int c = 0; c < TEDGE; ++c) {
                const float rv = radsh[c][r];   // 0 for c >= n
                w[c][0] = f2fma(rv, w0, w[c][0]);
                w[c][1] = f2fma(rv, w1, w[c][1]);
                w[c][2] = f2fma(rv, w2, w[c][2]);
            }
        }
        #pragma unroll
        for (int c = 0; c < TEDGE; ++c) {
            const float cut = cutsh[c];          // 0 for c >= n -> w row = 0
            w[c][0].x *= cut; w[c][0].y *= cut;
            w[c][1].x *= cut; w[c][1].y *= cut;
            w[c][2].x *= cut; w[c][2].y *= cut;
        }

        // ---- B2: build M for all n edges (8 threads per edge) ----
        {
            const int c = t >> 3;
            const int r = t & 7;
            if (c < n) {
                for (int kk = r; kk < ncg; kk += 8) {
                    atomicAdd(&M[c][cg_i3[kk] * MROW + cg_i1[kk]], cg_vals[kk] * Ysh[c][cg_i2[kk]]);
                }
            }
        }
        __syncthreads();

        // ---- C: branch-free fully-unrolled 8-edge contraction ----
        #pragma unroll
        for (int c = 0; c < TEDGE; ++c) {
            const int j = __builtin_amdgcn_readfirstlane(jsh[c]);

            const float2* xp = (const float2*)(x + (size_t)j * (S9 * NF)) + t;
            float2 xj[S9];
            #pragma unroll
            for (int s = 0; s < S9; ++s) xj[s] = xp[s * 64];

            #pragma unroll
            for (int s3 = 0; s3 < S9; ++s3) {
                const float4* mr = (const float4*)&M[c][s3 * MROW];
                const float4 m0 = mr[0];
                const float4 m1 = mr[1];
                const float  m8 = M[c][s3 * MROW + 8];
                float2 tsum = make_float2(0.f, 0.f);
                tsum = f2fma(m0.x, xj[0], tsum);
                tsum = f2fma(m0.y, xj[1], tsum);
                tsum = f2fma(m0.z, xj[2], tsum);
                tsum = f2fma(m0.w, xj[3], tsum);
                tsum = f2fma(m1.x, xj[4], tsum);
                tsum = f2fma(m1.y, xj[5], tsum);
                tsum = f2fma(m1.z, xj[6], tsum);
                tsum = f2fma(m1.w, xj[7], tsum);
                tsum = f2fma(m8,   xj[8], tsum);
                const float2 wl = (s3 == 0) ? w[c][0] : ((s3 < 4) ? w[c][1] : w[c][2]);
                acc[s3].x = fmaf(wl.x, tsum.x, acc[s3].x);
                acc[s3].y = fmaf(wl.y, tsum.y, acc[s3].y);
            }
        }
        __syncthreads();     // protect M/stage before next tile overwrites
    }

    // ---- store the atom's full output row (zeros for deg-0 atoms) ----
    float2* op = (float2*)(out + (size_t)a * (S9 * NF)) + t;
    #pragma unroll
    for (int s = 0; s < S9; ++s) op[s * 64] = acc[s];
}

extern "C" void kernel_launch(void* const* d_in, const int* in_sizes, int n_in,
                              void* d_out, int out_size, void* d_ws, size_t ws_size,
                              hipStream_t stream) {
    const float* x       = (const float*)d_in[0];
    const float* radial  = (const float*)d_in[1];
    const float* dir     = (const float*)d_in[2];
    const float* cutoff  = (const float*)d_in[3];
    const float* Wf      = (const float*)d_in[4];
    const float* bf      = (const float*)d_in[5];
    const float* cg_vals = (const float*)d_in[6];
    const int*   idx_i   = (const int*)d_in[7];
    const int*   idx_j   = (const int*)d_in[8];
    const int*   cg_i1   = (const int*)d_in[9];
    const int*   cg_i2   = (const int*)d_in[10];
    const int*   cg_i3   = (const int*)d_in[11];
    // d_in[12] = w_idx: unused (w_idx[k] == l(cg_idx_out[k]), folded into kernel)

    const int E   = in_sizes[7];
    const int ncg = in_sizes[6];
    const int A   = in_sizes[0] / (S9 * NF);

    // ws ints: offsets[A+1] | esorted[E]
    int* offsets = (int*)d_ws;
    int* esorted = offsets + (A + 1);

    csr_kernel<<<1, 1024, 0, stream>>>(idx_i, E, A, offsets, esorted);

    so3_atom_kernel<<<A, 64, 0, stream>>>(
        x, radial, dir, cutoff, Wf, bf, cg_vals, idx_j,
        cg_i1, cg_i2, cg_i3, ncg, offsets, esorted, (float*)d_out);
}